// Round 3
// baseline (403.174 us; speedup 1.0000x reference)
//
#include <hip/hip_runtime.h>
#include <hip/hip_bf16.h>

typedef unsigned short u16;
typedef unsigned int u32;
typedef __bf16 bf16x8 __attribute__((ext_vector_type(8)));
typedef float f32x4 __attribute__((ext_vector_type(4)));

#define N_ 32
#define D_ 512
#define P_ 3136   // 56*56
#define K_ 64
#define TILES_P 49          // 3136 / 64
#define NDP (D_ * P_)       // 1605632

// ---- workspace layout (bytes) ----
// wbf   : bf16 conv_w [64][512]                      @ 0        (65536)
// a_ws  : bf16 a' [32][64][3136]                     @ 65536    (12845056)
// a_sum : f32 [32][64]                               @ 12910592 (8192)
// agg   : f32 agg_part [7][32][64][512]              @ 12918784 (29360128)
// rowsq : f32 [32][64]                               @ 42278912 (8192)

__device__ __forceinline__ u16 f2bf(float f) {       // RNE float->bf16 bits
  u32 u = __float_as_uint(f);
  return (u16)((u + 0x7fffu + ((u >> 16) & 1u)) >> 16);
}
__device__ __forceinline__ u32 pack2(float a, float b) {
  return (u32)f2bf(a) | ((u32)f2bf(b) << 16);
}

// -------- KW: conv_w fp32 -> bf16 (64KB, L2-resident for K1) --------
__global__ __launch_bounds__(256) void kw_kernel(const float* __restrict__ w,
                                                 u16* __restrict__ wbf) {
  int i = blockIdx.x * 256 + threadIdx.x;            // 8192 threads * 4 elems
  float4 v = ((const float4*)w)[i];
  ((uint2*)wbf)[i] = make_uint2(pack2(v.x, v.y), pack2(v.z, v.w));
}

// -------- K1: logits GEMM + softmax -> a' (bf16), a_sum --------
// Bulk-stage the 64px x 512d tile into swizzled bf16 LDS (32 coalesced
// float4 loads/thread, max MLP), then barrier-free MFMA K-loop.
// LDS X layout: byte(p,d) = p*1024 + ((d>>3 ^ (p&7))<<4) + (d&7)*2
__global__ __launch_bounds__(256) void k1_kernel(const float* __restrict__ x,
                                                 const u16* __restrict__ wbf,
                                                 u16* __restrict__ a_ws,
                                                 float* __restrict__ a_sum) {
  __shared__ __align__(16) char xbuf[65536];   // bf16 X, later f32 a_stage[64][65]
  __shared__ float red[4][64];
  __shared__ float invn_s[64];
  u16* X = (u16*)xbuf;
  float (*a_stage)[65] = (float (*)[65])xbuf;

  const int t = threadIdx.x;
  const int lane = t & 63;
  const int w = t >> 6;
  const int c = lane & 15;
  const int q = lane >> 4;
  const int bid = blockIdx.x;
  const int n = bid / TILES_P;
  const int tile = bid - n * TILES_P;
  const int p0 = tile * 64;
  const int rp = w * 16 + c;            // pixel this lane serves in MFMA/softmax

  // ---- Phase A: bulk stage. thread covers px c*4..c*4+3, d rows g*64+w*16+q*4+i
  const float* xg = x + (size_t)n * NDP + p0 + c * 4;
  float La[8][4][4];
#pragma unroll
  for (int g = 0; g < 8; ++g) {
    const int dr = g * 64 + w * 16 + q * 4;
#pragma unroll
    for (int i = 0; i < 4; ++i) {
      float4 v4 = *(const float4*)(xg + (size_t)(dr + i) * P_);
      La[g][i][0] = v4.x; La[g][i][1] = v4.y; La[g][i][2] = v4.z; La[g][i][3] = v4.w;
    }
  }
  float ss[4] = {0.f, 0.f, 0.f, 0.f};
#pragma unroll
  for (int g = 0; g < 8; ++g) {
    const int dr = g * 64 + w * 16 + q * 4;
    const int chunk = dr >> 3;
    const int sub = (q & 1) * 8;        // (dr&7)*2 bytes
#pragma unroll
    for (int j = 0; j < 4; ++j) {
      float v0 = La[g][0][j], v1 = La[g][1][j], v2 = La[g][2][j], v3 = La[g][3][j];
      ss[j] += v0 * v0 + v1 * v1 + v2 * v2 + v3 * v3;
      const int p = c * 4 + j;
      const int byte = p * 1024 + (((chunk ^ (p & 7)) << 4) | sub);
      *(uint2*)(xbuf + byte) = make_uint2(pack2(v0, v1), pack2(v2, v3));
    }
  }
  // per-pixel sumsq partials: reduce over q (lane bits 4,5), cross-wave via LDS
#pragma unroll
  for (int j = 0; j < 4; ++j) {
    ss[j] += __shfl_xor(ss[j], 16);
    ss[j] += __shfl_xor(ss[j], 32);
  }
  if (q == 0) {
#pragma unroll
    for (int j = 0; j < 4; ++j) red[w][c * 4 + j] = ss[j];
  }
  __syncthreads();                      // X staged + red ready

  const float sumsq = red[0][rp] + red[1][rp] + red[2][rp] + red[3][rp];
  const float inv_p = 1.f / fmaxf(sqrtf(sumsq), 1e-12f);
  if (q == 0) invn_s[rp] = inv_p;

  // ---- Phase B: MFMA K-loop, no barriers; afrag prefetched 1 step ahead
  f32x4 acc[4];
#pragma unroll
  for (int m = 0; m < 4; ++m) acc[m] = (f32x4){0.f, 0.f, 0.f, 0.f};
  const int ds_base = rp * 1024;
  const int rmask = rp & 7;
  bf16x8 af[4];
#pragma unroll
  for (int m = 0; m < 4; ++m) af[m] = ((const bf16x8*)wbf)[(m * 16 + c) * 64 + q];
#pragma unroll
  for (int s = 0; s < 16; ++s) {
    bf16x8 afn[4];
    if (s < 15) {
#pragma unroll
      for (int m = 0; m < 4; ++m)
        afn[m] = ((const bf16x8*)wbf)[(m * 16 + c) * 64 + (s + 1) * 4 + q];
    }
    bf16x8 bfrag = *(const bf16x8*)(xbuf + ds_base + (((s * 4 + q) ^ rmask) << 4));
#pragma unroll
    for (int m = 0; m < 4; ++m)
      acc[m] = __builtin_amdgcn_mfma_f32_16x16x32_bf16(af[m], bfrag, acc[m], 0, 0, 0);
    if (s < 15) {
#pragma unroll
      for (int m = 0; m < 4; ++m) af[m] = afn[m];
    }
  }

  // ---- softmax over k: lanes q + regs (m,r) hold all 64 k of pixel rp
  float sc[4][4];
  float lmax = -3.0e38f;
#pragma unroll
  for (int m = 0; m < 4; ++m)
#pragma unroll
    for (int r = 0; r < 4; ++r) {
      float val = acc[m][r] * inv_p;
      sc[m][r] = val;
      lmax = fmaxf(lmax, val);
    }
  lmax = fmaxf(lmax, __shfl_xor(lmax, 16));
  lmax = fmaxf(lmax, __shfl_xor(lmax, 32));
  float lsum = 0.f;
#pragma unroll
  for (int m = 0; m < 4; ++m)
#pragma unroll
    for (int r = 0; r < 4; ++r) {
      float e = __expf(sc[m][r] - lmax);
      sc[m][r] = e;
      lsum += e;
    }
  lsum += __shfl_xor(lsum, 16);
  lsum += __shfl_xor(lsum, 32);
  const float rs = 1.f / lsum;

  __syncthreads();                      // all X ds_reads done; safe to overwrite
#pragma unroll
  for (int m = 0; m < 4; ++m)
#pragma unroll
    for (int r = 0; r < 4; ++r)
      a_stage[m * 16 + q * 4 + r][rp] = sc[m][r] * rs;   // a (pre inv_n)
  __syncthreads();

  // write a' = a*inv_n as bf16 (coalesced 32B/thread) + a_sum atomics
  {
    const int k = t >> 2, pc = t & 3;
    float ssum = 0.f;
    u32 u[8];
#pragma unroll
    for (int jj = 0; jj < 8; ++jj) {
      int p = pc * 16 + jj * 2;
      float a0 = a_stage[k][p], a1 = a_stage[k][p + 1];
      ssum += a0 + a1;
      u[jj] = (u32)f2bf(a0 * invn_s[p]) | ((u32)f2bf(a1 * invn_s[p + 1]) << 16);
    }
    u16* dst = a_ws + (size_t)n * (K_ * P_) + k * P_ + p0 + pc * 16;
    ((uint4*)dst)[0] = make_uint4(u[0], u[1], u[2], u[3]);
    ((uint4*)dst)[1] = make_uint4(u[4], u[5], u[6], u[7]);
    ssum += __shfl_xor(ssum, 1);
    ssum += __shfl_xor(ssum, 2);
    if ((t & 3) == 0) atomicAdd(&a_sum[n * 64 + k], ssum);
  }
}

// -------- K2: agg[k,d] = sum_p a'[k,p] * x[d,p]; operands fragment-contiguous
// in global; 2-deep register prefetch; bijective XCD swizzle (1792 % 8 == 0).
__global__ __launch_bounds__(256) void k2_kernel(const float* __restrict__ x,
                                                 const u16* __restrict__ a_ws,
                                                 float* __restrict__ agg) {
  int bid = blockIdx.x;                 // 1792 = 32n * 8dblk * 7pp
  bid = (bid & 7) * 224 + (bid >> 3);   // XCD chunks: 4 consecutive n per XCD
  const int n = bid / 56;
  const int rem = bid - n * 56;
  const int dblk = rem / 7;
  const int pp = rem - dblk * 7;
  const int t = threadIdx.x;
  const int lane = t & 63, w = t >> 6;
  const int c = lane & 15, q = lane >> 4;
  const int d0 = dblk * 64 + w * 16;    // wave owns 16 d columns

  f32x4 acc[4];
#pragma unroll
  for (int m = 0; m < 4; ++m) acc[m] = (f32x4){0.f, 0.f, 0.f, 0.f};

  const bf16x8* arow = (const bf16x8*)(a_ws + (size_t)n * (K_ * P_)); // 392 frags/row
  const float4* xf = (const float4*)(x + ((size_t)n * D_ + d0 + c) * P_);
  const int it0 = pp * 14;

  float4 pb[2][2];
  bf16x8 pa[2][4];
#pragma unroll
  for (int k2 = 0; k2 < 2; ++k2) {
    pb[k2][0] = xf[(it0 + k2) * 8 + q * 2];
    pb[k2][1] = xf[(it0 + k2) * 8 + q * 2 + 1];
#pragma unroll
    for (int m = 0; m < 4; ++m)
      pa[k2][m] = arow[(m * 16 + c) * 392 + (it0 + k2) * 4 + q];
  }
#pragma unroll
  for (int ii = 0; ii < 14; ++ii) {
    const int cur = ii & 1;
    float4 b0 = pb[cur][0], b1 = pb[cur][1];
    bf16x8 a0_ = pa[cur][0], a1_ = pa[cur][1], a2_ = pa[cur][2], a3_ = pa[cur][3];
    if (ii < 12) {
      pb[cur][0] = xf[(it0 + ii + 2) * 8 + q * 2];
      pb[cur][1] = xf[(it0 + ii + 2) * 8 + q * 2 + 1];
#pragma unroll
      for (int m = 0; m < 4; ++m)
        pa[cur][m] = arow[(m * 16 + c) * 392 + (it0 + ii + 2) * 4 + q];
    }
    bf16x8 bfrag;
    bfrag[0] = (__bf16)b0.x; bfrag[1] = (__bf16)b0.y;
    bfrag[2] = (__bf16)b0.z; bfrag[3] = (__bf16)b0.w;
    bfrag[4] = (__bf16)b1.x; bfrag[5] = (__bf16)b1.y;
    bfrag[6] = (__bf16)b1.z; bfrag[7] = (__bf16)b1.w;
    acc[0] = __builtin_amdgcn_mfma_f32_16x16x32_bf16(a0_, bfrag, acc[0], 0, 0, 0);
    acc[1] = __builtin_amdgcn_mfma_f32_16x16x32_bf16(a1_, bfrag, acc[1], 0, 0, 0);
    acc[2] = __builtin_amdgcn_mfma_f32_16x16x32_bf16(a2_, bfrag, acc[2], 0, 0, 0);
    acc[3] = __builtin_amdgcn_mfma_f32_16x16x32_bf16(a3_, bfrag, acc[3], 0, 0, 0);
  }
  float* ob = agg + ((size_t)pp * 32 + n) * (K_ * D_);
#pragma unroll
  for (int m = 0; m < 4; ++m)
#pragma unroll
    for (int r = 0; r < 4; ++r)
      ob[(m * 16 + q * 4 + r) * D_ + d0 + c] = acc[m][r];
}

// -------- K3a: vlad = sum_pp agg[pp] - a_sum*c ; per-row sumsq --------
// one wave per (n,k) row of 512 floats.
__global__ __launch_bounds__(64) void k3a_kernel(const float* __restrict__ agg,
                                                 const float* __restrict__ a_sum,
                                                 const float* __restrict__ cent,
                                                 float* __restrict__ out,
                                                 float* __restrict__ rowsq) {
  const int b = blockIdx.x;             // n*64 + k
  const int n = b >> 6, k = b & 63;
  const int t = threadIdx.x;            // 64 lanes, 8 floats each
  const float* ab = agg + ((size_t)n * 64 + k) * 512 + t * 8;
  float v[8];
#pragma unroll
  for (int j = 0; j < 8; ++j) v[j] = 0.f;
#pragma unroll
  for (int pp = 0; pp < 7; ++pp) {
    const float4* p4 = (const float4*)(ab + (size_t)pp * 32 * (K_ * D_));
    float4 r0 = p4[0], r1 = p4[1];
    v[0] += r0.x; v[1] += r0.y; v[2] += r0.z; v[3] += r0.w;
    v[4] += r1.x; v[5] += r1.y; v[6] += r1.z; v[7] += r1.w;
  }
  const float asum = a_sum[b];
  const float4* c4 = (const float4*)(cent + k * 512 + t * 8);
  float4 c0 = c4[0], c1 = c4[1];
  v[0] -= asum * c0.x; v[1] -= asum * c0.y; v[2] -= asum * c0.z; v[3] -= asum * c0.w;
  v[4] -= asum * c1.x; v[5] -= asum * c1.y; v[6] -= asum * c1.z; v[7] -= asum * c1.w;
  float ssq = 0.f;
#pragma unroll
  for (int j = 0; j < 8; ++j) ssq += v[j] * v[j];
  ssq += __shfl_xor(ssq, 1);  ssq += __shfl_xor(ssq, 2);  ssq += __shfl_xor(ssq, 4);
  ssq += __shfl_xor(ssq, 8);  ssq += __shfl_xor(ssq, 16); ssq += __shfl_xor(ssq, 32);
  float4* o4 = (float4*)(out + (size_t)n * 32768 + k * 512 + t * 8);
  o4[0] = make_float4(v[0], v[1], v[2], v[3]);
  o4[1] = make_float4(v[4], v[5], v[6], v[7]);
  if (t == 0) rowsq[b] = ssq;
}

// -------- K3b: intra + global normalize (scale in place) --------
__global__ __launch_bounds__(256) void k3b_kernel(const float* __restrict__ rowsq,
                                                  float* __restrict__ out) {
  __shared__ float invr_s[64];
  __shared__ float gi_s;
  const int n = blockIdx.x >> 3;
  const int seg = blockIdx.x & 7;       // 4096 floats per segment
  const int t = threadIdx.x;
  if (t < 64) {
    float r = rowsq[n * 64 + t];
    float ri = 1.f / fmaxf(sqrtf(r), 1e-12f);
    invr_s[t] = ri;
    float g = r * ri * ri;
    g += __shfl_xor(g, 1); g += __shfl_xor(g, 2); g += __shfl_xor(g, 4);
    g += __shfl_xor(g, 8); g += __shfl_xor(g, 16); g += __shfl_xor(g, 32);
    if (t == 0) gi_s = 1.f / fmaxf(sqrtf(g), 1e-12f);
  }
  __syncthreads();
  const int e0 = seg * 4096 + t * 16;   // 16 consecutive floats, same k (16|512)
  const float sc = invr_s[e0 >> 9] * gi_s;
  float4* o4 = (float4*)(out + (size_t)n * 32768 + e0);
#pragma unroll
  for (int i = 0; i < 4; ++i) {
    float4 vv = o4[i];
    vv.x *= sc; vv.y *= sc; vv.z *= sc; vv.w *= sc;
    o4[i] = vv;
  }
}

extern "C" void kernel_launch(void* const* d_in, const int* in_sizes, int n_in,
                              void* d_out, int out_size, void* d_ws, size_t ws_size,
                              hipStream_t stream) {
  (void)in_sizes; (void)n_in; (void)out_size; (void)ws_size;
  const float* x    = (const float*)d_in[0];
  const float* cw   = (const float*)d_in[1];
  const float* cent = (const float*)d_in[2];
  float* out = (float*)d_out;
  char* ws = (char*)d_ws;
  u16*   wbf   = (u16*)(ws);
  u16*   a_ws  = (u16*)(ws + 65536);
  float* a_sum = (float*)(ws + 12910592);
  float* agg   = (float*)(ws + 12918784);
  float* rowsq = (float*)(ws + 42278912);

  hipMemsetAsync(a_sum, 0, 64 * 32 * sizeof(float), stream);  // atomics target
  kw_kernel<<<32, 256, 0, stream>>>(cw, wbf);
  k1_kernel<<<32 * TILES_P, 256, 0, stream>>>(x, wbf, a_ws, a_sum);
  k2_kernel<<<1792, 256, 0, stream>>>(x, a_ws, agg);
  k3a_kernel<<<2048, 64, 0, stream>>>(agg, a_sum, cent, out, rowsq);
  k3b_kernel<<<256, 256, 0, stream>>>(rowsq, out);
}